// Round 5
// baseline (189.252 us; speedup 1.0000x reference)
//
#include <hip/hip_runtime.h>
#include <cmath>

#define ENTRIES 27
#define ACTION  4096
#define BATCH   8192
#define SDIM    322
#define KPAD    360      // 322 padded; 720B row stride -> ~2-way LDS conflict (free)
#define NNODES  256

typedef unsigned short u16;
typedef u16 u16x4 __attribute__((ext_vector_type(4)));
typedef u16 u16x8 __attribute__((ext_vector_type(8)));
typedef __bf16 bf16x8 __attribute__((ext_vector_type(8)));
typedef float floatx2 __attribute__((ext_vector_type(2)));
typedef float floatx4 __attribute__((ext_vector_type(4)));

__device__ __forceinline__ u16 f2bf(float f) {
    unsigned u = __builtin_bit_cast(unsigned, f);
    unsigned r = (u + 0x7FFFu + ((u >> 16) & 1u)) >> 16;   // RNE
    return (u16)r;
}
__device__ __forceinline__ float sig500(float v) {
    return __fdividef(500.0f, 1.0f + __expf(-v));
}
__device__ __forceinline__ float ftanh(float x) {
    return 1.0f - __fdividef(2.0f, __expf(2.0f * x) + 1.0f);
}
// async global->LDS, 16 B per lane; LDS dest = wave-uniform base + lane*16
__device__ __forceinline__ void gl_lds16(const u16* g, u16* l) {
    __builtin_amdgcn_global_load_lds(
        (const __attribute__((address_space(1))) unsigned int*)g,
        (__attribute__((address_space(3))) unsigned int*)l, 16, 0, 0);
}

// ---------------------------------------------------------------------------
// Prep: blocks [0,32): Wg[256,KPAD] bf16 scatter-build (8 nodes/blk)
//       blocks [32,1056): Wf f32[4096,256] -> bf16
// ---------------------------------------------------------------------------
#define PREP_WF0 32
#define PREP_TOT 1056

__global__ __launch_bounds__(256) void prep_kernel(
    const float* __restrict__ W, const int* __restrict__ idx,
    const float* __restrict__ wf,
    u16* __restrict__ wg, u16* __restrict__ wfb)
{
    const int tid = threadIdx.x;
    const int bid = blockIdx.x;

    if (bid < PREP_WF0) {
        __shared__ float rows[8 * KPAD];               // 11520 B
        for (int i = tid; i < 8 * KPAD; i += 256) rows[i] = 0.f;
        __syncthreads();
        if (tid < 8 * ENTRIES) {                       // 216 active
            const int nl = tid / ENTRIES;
            const int e  = tid - nl * ENTRIES;
            const int n  = bid * 8 + nl;
            atomicAdd(&rows[nl * KPAD + idx[n * ENTRIES + e]],
                      W[n * ENTRIES + e]);
        }
        __syncthreads();
        for (int i = tid; i < 8 * KPAD; i += 256)
            wg[(size_t)bid * 8 * KPAD + i] = f2bf(rows[i]);
    } else {
        const int i0 = ((bid - PREP_WF0) * 256 + tid) * 4;
        floatx4 v = *(const floatx4*)(wf + i0);
        u16x4 r;
        r.x = f2bf(v.x); r.y = f2bf(v.y); r.z = f2bf(v.z); r.w = f2bf(v.w);
        *(u16x4*)(wfb + i0) = r;
    }
}

// ---------------------------------------------------------------------------
// gemm1 (verified R2 structure, KPAD=360): y = tanh(state . WgT + b), bf16.
//  A = state f32 converted in regs (loads fly under MFMA);
//  B = Wg slice [64 x KPAD] bf16, LDS-resident (one prologue stage).
// ---------------------------------------------------------------------------
__global__ __launch_bounds__(256) void gemm1_fused(
    const float* __restrict__ state, const u16* __restrict__ wg,
    u16* __restrict__ y, const float* __restrict__ bias)
{
    __shared__ u16 Bs[64 * KPAD];   // 46080 B, resident the whole loop
    __shared__ u16 As[64 * 32];     // 4096 B, one K-step

    const int bm   = blockIdx.x;    // 128 row-tiles of 64
    const int bn   = blockIdx.y;    // 4 node-tiles of 64
    const int tid  = threadIdx.x;
    const int lane = tid & 63;
    const int wave = tid >> 6;
    const int wm   = wave & 1;
    const int wn   = wave >> 1;
    const int l15  = lane & 15;
    const int koff = (lane >> 4) << 3;

    // prologue: stage resident B (45 KiB contiguous)
    const u16* wgp = wg + (size_t)bn * 64 * KPAD;
    for (int c = wave; c < 45; c += 4)
        gl_lds16(wgp + c * 512 + lane * 8, &Bs[c * 512]);

    // A register prefetch: thread -> (row = tid>>2, 8 cols)
    const int arow = tid >> 2;
    const int qseg = tid & 3;
    const float* ap = state + (size_t)(bm * 64 + arow) * SDIM + qseg * 8;
    float va[8];
    auto loada = [&](int kk) {
        const int c0 = kk + qseg * 8;
        const float* p = ap + kk;
        if (c0 + 8 <= SDIM) {
#pragma unroll
            for (int j = 0; j < 4; j++)
                *(floatx2*)&va[2 * j] = *(const floatx2*)(p + 2 * j);
        } else {
#pragma unroll
            for (int j = 0; j < 8; j++)
                va[j] = (c0 + j < SDIM) ? p[j] : 0.f;   // zero-pad tail
        }
    };
    loada(0);

    floatx4 acc[2][2];
#pragma unroll
    for (int mi = 0; mi < 2; mi++)
#pragma unroll
        for (int ni = 0; ni < 2; ni++)
            acc[mi][ni] = (floatx4){0.f, 0.f, 0.f, 0.f};

#pragma unroll
    for (int s = 0; s < 11; s++) {
        const int kk = s * 32;
        u16x8 pk;                      // cvt prefetched A (vmcnt waits here)
#pragma unroll
        for (int j = 0; j < 8; j++) ((u16*)&pk)[j] = f2bf(va[j]);

        __syncthreads();               // prev iter's ds_reads done (+B at s=0)
        *(u16x8*)&As[arow * 32 + qseg * 8] = pk;
        __syncthreads();               // As(k) visible

        if (s < 10) loada(kk + 32);    // next loads fly under MFMA

        bf16x8 af[2], bfr[2];
#pragma unroll
        for (int mi = 0; mi < 2; mi++)
            af[mi] = __builtin_bit_cast(bf16x8,
                *(const u16x8*)&As[((wm << 5) + (mi << 4) + l15) * 32 + koff]);
#pragma unroll
        for (int ni = 0; ni < 2; ni++)
            bfr[ni] = __builtin_bit_cast(bf16x8,
                *(const u16x8*)&Bs[(wn * 32 + ni * 16 + l15) * KPAD + kk + koff]);
#pragma unroll
        for (int mi = 0; mi < 2; mi++)
#pragma unroll
            for (int ni = 0; ni < 2; ni++)
                acc[mi][ni] = __builtin_amdgcn_mfma_f32_16x16x32_bf16(
                    af[mi], bfr[ni], acc[mi][ni], 0, 0, 0);
    }

    // epilogue: C/D layout col=lane&15, row=(lane>>4)*4+reg
    const int r0 = (lane >> 4) << 2;
    float bv[2];
#pragma unroll
    for (int ni = 0; ni < 2; ni++)
        bv[ni] = bias[bn * 64 + wn * 32 + ni * 16 + l15];
#pragma unroll
    for (int mi = 0; mi < 2; mi++)
#pragma unroll
        for (int ni = 0; ni < 2; ni++) {
            const int row = bm * 64 + wm * 32 + mi * 16 + r0;
            const int col = bn * 64 + wn * 32 + ni * 16 + l15;
#pragma unroll
            for (int r = 0; r < 4; r++)
                y[(size_t)(row + r) * NNODES + col] =
                    f2bf(ftanh(acc[mi][ni][r] + bv[ni]));
        }
}

// ---------------------------------------------------------------------------
// gemm2 v2: out = 500*sigmoid(y . WfT), 128x128 tile, K=256.
//  * double-buffered LDS (2x16KB): STAGE(next) issued BEFORE compute(cur);
//    single __syncthreads() per K-step whose implicit vmcnt(0) lands AFTER
//    the MFMA phase -> load latency hidden (T3-minimum, plain-HIP form).
//  * XCD-chunked bijective (bm,bn) map: each XCD owns 4 bn-panels (256 KB)
//    + streams y (4 MB) ~= its private 4 MiB L2.
//  * nontemporal f32 output stores (134 MB stream doesn't evict L2).
// ---------------------------------------------------------------------------
__global__ __launch_bounds__(256) void gemm2(
    const u16* __restrict__ A, const u16* __restrict__ B,
    float* __restrict__ out)
{
    __shared__ u16 As[2][128 * 32];   // 2 x 8 KB
    __shared__ u16 Bs[2][128 * 32];   // 2 x 8 KB

    const int gid  = blockIdx.x;      // 2048
    const int xcd  = gid & 7;
    const int li   = gid >> 3;        // 0..255
    const int bn   = (xcd << 2) | (li & 3);   // 0..31
    const int bm   = li >> 2;                 // 0..63
    const int tid  = threadIdx.x;
    const int lane = tid & 63;
    const int wave = tid >> 6;
    const int wm   = wave & 1;
    const int wn   = wave >> 1;
    const int l15  = lane & 15;
    const int koff = (lane >> 4) << 3;
    const int crow = lane >> 2;
    const int ckel = (lane & 3) << 3;

    auto stage = [&](int buf, int kk) {
#pragma unroll
        for (int c = wave; c < 16; c += 4) {
            const bool isA = c < 8;
            const int  cr  = isA ? c : c - 8;
            const int  row = cr * 16 + crow;
            const u16* g = isA
                ? (A + ((size_t)bm * 128 + row) * 256 + kk + ckel)
                : (B + ((size_t)bn * 128 + row) * 256 + kk + ckel);
            gl_lds16(g, isA ? &As[buf][cr * 512] : &Bs[buf][cr * 512]);
        }
    };

    floatx4 acc[4][4];
#pragma unroll
    for (int mi = 0; mi < 4; mi++)
#pragma unroll
        for (int ni = 0; ni < 4; ni++)
            acc[mi][ni] = (floatx4){0.f, 0.f, 0.f, 0.f};

    stage(0, 0);
    __syncthreads();                       // drains prologue loads

#pragma unroll
    for (int s = 0; s < 8; s++) {
        const int cur = s & 1;
        if (s < 7) stage(cur ^ 1, (s + 1) * 32);   // fly under compute

        bf16x8 af[4], bfg[4];
#pragma unroll
        for (int mi = 0; mi < 4; mi++)
            af[mi] = __builtin_bit_cast(bf16x8,
                *(const u16x8*)&As[cur][((wm << 6) + (mi << 4) + l15) * 32 + koff]);
#pragma unroll
        for (int ni = 0; ni < 4; ni++)
            bfg[ni] = __builtin_bit_cast(bf16x8,
                *(const u16x8*)&Bs[cur][(wn * 64 + (ni << 4) + l15) * 32 + koff]);

#pragma unroll
        for (int mi = 0; mi < 4; mi++)
#pragma unroll
            for (int ni = 0; ni < 4; ni++)
                acc[mi][ni] = __builtin_amdgcn_mfma_f32_16x16x32_bf16(
                    af[mi], bfg[ni], acc[mi][ni], 0, 0, 0);

        __syncthreads();   // implicit vmcnt(0): next buffer ready; reads done
    }

    const int r0 = (lane >> 4) << 2;
#pragma unroll
    for (int mi = 0; mi < 4; mi++)
#pragma unroll
        for (int ni = 0; ni < 4; ni++) {
            const int row = bm * 128 + wm * 64 + mi * 16 + r0;
            const int col = bn * 128 + wn * 64 + ni * 16 + l15;
#pragma unroll
            for (int r = 0; r < 4; r++)
                __builtin_nontemporal_store(sig500(acc[mi][ni][r]),
                    &out[(size_t)(row + r) * ACTION + col]);
        }
}

extern "C" void kernel_launch(void* const* d_in, const int* in_sizes, int n_in,
                              void* d_out, int out_size, void* d_ws, size_t ws_size,
                              hipStream_t stream) {
    const float* state = (const float*)d_in[0];
    const float* W     = (const float*)d_in[1];
    const float* b     = (const float*)d_in[2];
    const float* Wf    = (const float*)d_in[3];
    const int*   idx   = (const int*)  d_in[4];
    float* out = (float*)d_out;

    u16* wg  = (u16*)d_ws;                         // 256*KPAD bf16
    u16* y   = wg + (size_t)NNODES * KPAD;         // 8192*256 bf16
    u16* wfb = y  + (size_t)BATCH * NNODES;        // 4096*256 bf16

    prep_kernel<<<PREP_TOT, 256, 0, stream>>>(W, idx, Wf, wg, wfb);
    gemm1_fused<<<dim3(128, 4), 256, 0, stream>>>(state, wg, y, b);
    gemm2<<<2048, 256, 0, stream>>>(y, wfb, out);
}

// Round 6
// 177.223 us; speedup vs baseline: 1.0679x; 1.0679x over previous
//
#include <hip/hip_runtime.h>
#include <cmath>

#define ENTRIES 27
#define ACTION  4096
#define BATCH   8192
#define SDIM    322
#define KPAD    360      // 322 padded; 720B row stride -> ~2-way LDS conflict (free)
#define NNODES  256

typedef unsigned short u16;
typedef u16 u16x4 __attribute__((ext_vector_type(4)));
typedef u16 u16x8 __attribute__((ext_vector_type(8)));
typedef __bf16 bf16x8 __attribute__((ext_vector_type(8)));
typedef float floatx2 __attribute__((ext_vector_type(2)));
typedef float floatx4 __attribute__((ext_vector_type(4)));

__device__ __forceinline__ u16 f2bf(float f) {
    unsigned u = __builtin_bit_cast(unsigned, f);
    unsigned r = (u + 0x7FFFu + ((u >> 16) & 1u)) >> 16;   // RNE
    return (u16)r;
}
__device__ __forceinline__ float sig500(float v) {
    return __fdividef(500.0f, 1.0f + __expf(-v));
}
__device__ __forceinline__ float ftanh(float x) {
    return 1.0f - __fdividef(2.0f, __expf(2.0f * x) + 1.0f);
}
// async global->LDS, 16 B per lane; LDS dest = wave-uniform base + lane*16
__device__ __forceinline__ void gl_lds16(const u16* g, u16* l) {
    __builtin_amdgcn_global_load_lds(
        (const __attribute__((address_space(1))) unsigned int*)g,
        (__attribute__((address_space(3))) unsigned int*)l, 16, 0, 0);
}

// ---------------------------------------------------------------------------
// Prep: blocks [0,32): Wg[256,KPAD] bf16 scatter-build (8 nodes/blk)
//       blocks [32,1056): Wf f32[4096,256] -> bf16
// ---------------------------------------------------------------------------
#define PREP_WF0 32
#define PREP_TOT 1056

__global__ __launch_bounds__(256) void prep_kernel(
    const float* __restrict__ W, const int* __restrict__ idx,
    const float* __restrict__ wf,
    u16* __restrict__ wg, u16* __restrict__ wfb)
{
    const int tid = threadIdx.x;
    const int bid = blockIdx.x;

    if (bid < PREP_WF0) {
        __shared__ float rows[8 * KPAD];               // 11520 B
        for (int i = tid; i < 8 * KPAD; i += 256) rows[i] = 0.f;
        __syncthreads();
        if (tid < 8 * ENTRIES) {                       // 216 active
            const int nl = tid / ENTRIES;
            const int e  = tid - nl * ENTRIES;
            const int n  = bid * 8 + nl;
            atomicAdd(&rows[nl * KPAD + idx[n * ENTRIES + e]],
                      W[n * ENTRIES + e]);
        }
        __syncthreads();
        for (int i = tid; i < 8 * KPAD; i += 256)
            wg[(size_t)bid * 8 * KPAD + i] = f2bf(rows[i]);
    } else {
        const int i0 = ((bid - PREP_WF0) * 256 + tid) * 4;
        floatx4 v = *(const floatx4*)(wf + i0);
        u16x4 r;
        r.x = f2bf(v.x); r.y = f2bf(v.y); r.z = f2bf(v.z); r.w = f2bf(v.w);
        *(u16x4*)(wfb + i0) = r;
    }
}

// ---------------------------------------------------------------------------
// gemm1 (verified R2 structure, KPAD=360): y = tanh(state . WgT + b), bf16.
//  A = state f32 converted in regs (loads fly under MFMA);
//  B = Wg slice [64 x KPAD] bf16, LDS-resident (one prologue stage).
// ---------------------------------------------------------------------------
__global__ __launch_bounds__(256) void gemm1_fused(
    const float* __restrict__ state, const u16* __restrict__ wg,
    u16* __restrict__ y, const float* __restrict__ bias)
{
    __shared__ u16 Bs[64 * KPAD];   // 46080 B, resident the whole loop
    __shared__ u16 As[64 * 32];     // 4096 B, one K-step

    const int bm   = blockIdx.x;    // 128 row-tiles of 64
    const int bn   = blockIdx.y;    // 4 node-tiles of 64
    const int tid  = threadIdx.x;
    const int lane = tid & 63;
    const int wave = tid >> 6;
    const int wm   = wave & 1;
    const int wn   = wave >> 1;
    const int l15  = lane & 15;
    const int koff = (lane >> 4) << 3;

    // prologue: stage resident B (45 KiB contiguous)
    const u16* wgp = wg + (size_t)bn * 64 * KPAD;
    for (int c = wave; c < 45; c += 4)
        gl_lds16(wgp + c * 512 + lane * 8, &Bs[c * 512]);

    // A register prefetch: thread -> (row = tid>>2, 8 cols)
    const int arow = tid >> 2;
    const int qseg = tid & 3;
    const float* ap = state + (size_t)(bm * 64 + arow) * SDIM + qseg * 8;
    float va[8];
    auto loada = [&](int kk) {
        const int c0 = kk + qseg * 8;
        const float* p = ap + kk;
        if (c0 + 8 <= SDIM) {
#pragma unroll
            for (int j = 0; j < 4; j++)
                *(floatx2*)&va[2 * j] = *(const floatx2*)(p + 2 * j);
        } else {
#pragma unroll
            for (int j = 0; j < 8; j++)
                va[j] = (c0 + j < SDIM) ? p[j] : 0.f;   // zero-pad tail
        }
    };
    loada(0);

    floatx4 acc[2][2];
#pragma unroll
    for (int mi = 0; mi < 2; mi++)
#pragma unroll
        for (int ni = 0; ni < 2; ni++)
            acc[mi][ni] = (floatx4){0.f, 0.f, 0.f, 0.f};

#pragma unroll
    for (int s = 0; s < 11; s++) {
        const int kk = s * 32;
        u16x8 pk;                      // cvt prefetched A (vmcnt waits here)
#pragma unroll
        for (int j = 0; j < 8; j++) ((u16*)&pk)[j] = f2bf(va[j]);

        __syncthreads();               // prev iter's ds_reads done (+B at s=0)
        *(u16x8*)&As[arow * 32 + qseg * 8] = pk;
        __syncthreads();               // As(k) visible

        if (s < 10) loada(kk + 32);    // next loads fly under MFMA

        bf16x8 af[2], bfr[2];
#pragma unroll
        for (int mi = 0; mi < 2; mi++)
            af[mi] = __builtin_bit_cast(bf16x8,
                *(const u16x8*)&As[((wm << 5) + (mi << 4) + l15) * 32 + koff]);
#pragma unroll
        for (int ni = 0; ni < 2; ni++)
            bfr[ni] = __builtin_bit_cast(bf16x8,
                *(const u16x8*)&Bs[(wn * 32 + ni * 16 + l15) * KPAD + kk + koff]);
#pragma unroll
        for (int mi = 0; mi < 2; mi++)
#pragma unroll
            for (int ni = 0; ni < 2; ni++)
                acc[mi][ni] = __builtin_amdgcn_mfma_f32_16x16x32_bf16(
                    af[mi], bfr[ni], acc[mi][ni], 0, 0, 0);
    }

    // epilogue: C/D layout col=lane&15, row=(lane>>4)*4+reg
    const int r0 = (lane >> 4) << 2;
    float bv[2];
#pragma unroll
    for (int ni = 0; ni < 2; ni++)
        bv[ni] = bias[bn * 64 + wn * 32 + ni * 16 + l15];
#pragma unroll
    for (int mi = 0; mi < 2; mi++)
#pragma unroll
        for (int ni = 0; ni < 2; ni++) {
            const int row = bm * 64 + wm * 32 + mi * 16 + r0;
            const int col = bn * 64 + wn * 32 + ni * 16 + l15;
#pragma unroll
            for (int r = 0; r < 4; r++)
                y[(size_t)(row + r) * NNODES + col] =
                    f2bf(ftanh(acc[mi][ni][r] + bv[ni]));
        }
}

// ---------------------------------------------------------------------------
// gemm2: out = 500*sigmoid(y . WfT) — EXACT R2 structure (single 16 KB
// buffer, 8 blocks/CU, plain stores), with ONE change: bijective XCD-chunked
// (bm,bn) mapping (T1). Each XCD owns 4 consecutive bn panels (wfb slice
// 256 KB -> L2-resident); all XCDs sweep bm in lockstep so y tiles ride
// L2/L3 instead of being re-fetched per bn-block.
// ---------------------------------------------------------------------------
__global__ __launch_bounds__(256) void gemm2(
    const u16* __restrict__ A, const u16* __restrict__ B,
    float* __restrict__ out)
{
    __shared__ u16 As[128 * 32];
    __shared__ u16 Bs[128 * 32];

    const int gid  = blockIdx.x;              // 2048
    const int xcd  = gid & 7;                 // dispatch round-robins XCDs
    const int li   = gid >> 3;                // 0..255, bm-major within XCD
    const int bn   = (xcd << 2) | (li & 3);   // 0..31: 4 panels per XCD
    const int bm   = li >> 2;                 // 0..63: lockstep across XCDs
    const int tid  = threadIdx.x;
    const int lane = tid & 63;
    const int wave = tid >> 6;
    const int wm   = wave & 1;
    const int wn   = wave >> 1;
    const int l15  = lane & 15;
    const int koff = (lane >> 4) << 3;

    floatx4 acc[4][4];
#pragma unroll
    for (int mi = 0; mi < 4; mi++)
#pragma unroll
        for (int ni = 0; ni < 4; ni++)
            acc[mi][ni] = (floatx4){0.f, 0.f, 0.f, 0.f};

    const int crow = lane >> 2;
    const int ckel = (lane & 3) << 3;

#pragma unroll
    for (int kk = 0; kk < 256; kk += 32) {
        __syncthreads();
#pragma unroll
        for (int c = wave; c < 16; c += 4) {
            const bool isA = c < 8;
            const int  cr  = isA ? c : c - 8;
            const int  row = cr * 16 + crow;
            const u16* g = isA
                ? (A + ((size_t)bm * 128 + row) * 256 + kk + ckel)
                : (B + ((size_t)bn * 128 + row) * 256 + kk + ckel);
            gl_lds16(g, isA ? &As[cr * 512] : &Bs[cr * 512]);
        }
        __syncthreads();

        bf16x8 af[4], bfg[4];
#pragma unroll
        for (int mi = 0; mi < 4; mi++)
            af[mi] = __builtin_bit_cast(bf16x8,
                *(const u16x8*)&As[((wm << 6) + (mi << 4) + l15) * 32 + koff]);
#pragma unroll
        for (int ni = 0; ni < 4; ni++)
            bfg[ni] = __builtin_bit_cast(bf16x8,
                *(const u16x8*)&Bs[(wn * 64 + (ni << 4) + l15) * 32 + koff]);

#pragma unroll
        for (int mi = 0; mi < 4; mi++)
#pragma unroll
            for (int ni = 0; ni < 4; ni++)
                acc[mi][ni] = __builtin_amdgcn_mfma_f32_16x16x32_bf16(
                    af[mi], bfg[ni], acc[mi][ni], 0, 0, 0);
    }

    const int r0 = (lane >> 4) << 2;
#pragma unroll
    for (int mi = 0; mi < 4; mi++)
#pragma unroll
        for (int ni = 0; ni < 4; ni++) {
            const int row = bm * 128 + wm * 64 + mi * 16 + r0;
            const int col = bn * 128 + wn * 64 + ni * 16 + l15;
#pragma unroll
            for (int r = 0; r < 4; r++)
                out[(size_t)(row + r) * ACTION + col] = sig500(acc[mi][ni][r]);
        }
}

extern "C" void kernel_launch(void* const* d_in, const int* in_sizes, int n_in,
                              void* d_out, int out_size, void* d_ws, size_t ws_size,
                              hipStream_t stream) {
    const float* state = (const float*)d_in[0];
    const float* W     = (const float*)d_in[1];
    const float* b     = (const float*)d_in[2];
    const float* Wf    = (const float*)d_in[3];
    const int*   idx   = (const int*)  d_in[4];
    float* out = (float*)d_out;

    u16* wg  = (u16*)d_ws;                         // 256*KPAD bf16
    u16* y   = wg + (size_t)NNODES * KPAD;         // 8192*256 bf16
    u16* wfb = y  + (size_t)BATCH * NNODES;        // 4096*256 bf16

    prep_kernel<<<PREP_TOT, 256, 0, stream>>>(W, idx, Wf, wg, wfb);
    gemm1_fused<<<dim3(128, 4), 256, 0, stream>>>(state, wg, y, b);
    gemm2<<<2048, 256, 0, stream>>>(y, wfb, out);
}